// Round 1
// baseline (1860.314 us; speedup 1.0000x reference)
//
#include <hip/hip_runtime.h>
#include <math.h>

#define DIM 512
#define NHEAD 8
#define HD 64
#define NBANK 4096
#define NQROWS 4096
#define EPS 1e-5f
#define QSCALE 0.125f

// ---------------------------------------------------------------------------
// proj_ln_kernel: Y[row,o] = LN_head( sum_k X[row,k] * W[o,k] )
// MODE 0: per-head LN (gamma,beta) then * QSCALE   (Q path)
// MODE 1: per-head LN (gamma,beta)                 (K path)
// MODE 2: plain GEMM                               (V path)
// Block: 256 threads, 16 rows. Thread owns output cols tid and tid+256.
// ---------------------------------------------------------------------------
template<int MODE>
__global__ __launch_bounds__(256) void proj_ln_kernel(
    const float* __restrict__ X, const float* __restrict__ W,
    const float* __restrict__ gamma, const float* __restrict__ beta,
    float* __restrict__ Y)
{
    __shared__ __align__(16) float xs[16 * DIM];   // 32 KB
    __shared__ float stat_m[16 * NHEAD];
    __shared__ float stat_r[16 * NHEAD];
    const int tid  = threadIdx.x;
    const int row0 = blockIdx.x * 16;

    {   // stage 16 input rows, coalesced float4
        const float4* src = (const float4*)(X + (size_t)row0 * DIM);
        float4* dst = (float4*)xs;
        for (int i = tid; i < 16 * DIM / 4; i += 256) dst[i] = src[i];
    }
    __syncthreads();

    const int c0 = tid, c1 = tid + 256;
    float acc0[16], acc1[16];
    #pragma unroll
    for (int r = 0; r < 16; ++r) { acc0[r] = 0.f; acc1[r] = 0.f; }

    const float* w0 = W + (size_t)c0 * DIM;
    const float* w1 = W + (size_t)c1 * DIM;
    for (int k = 0; k < DIM; k += 4) {
        const float4 wv0 = *(const float4*)(w0 + k);
        const float4 wv1 = *(const float4*)(w1 + k);
        #pragma unroll
        for (int r = 0; r < 16; ++r) {
            const float4 xv = *(const float4*)(xs + r * DIM + k);
            acc0[r] = fmaf(xv.x, wv0.x, fmaf(xv.y, wv0.y, fmaf(xv.z, wv0.z, fmaf(xv.w, wv0.w, acc0[r]))));
            acc1[r] = fmaf(xv.x, wv1.x, fmaf(xv.y, wv1.y, fmaf(xv.z, wv1.z, fmaf(xv.w, wv1.w, acc1[r]))));
        }
    }

    if (MODE == 2) {
        #pragma unroll
        for (int r = 0; r < 16; ++r) {
            Y[(size_t)(row0 + r) * DIM + c0] = acc0[r];
            Y[(size_t)(row0 + r) * DIM + c1] = acc1[r];
        }
        return;
    }

    __syncthreads();            // done reading xs as input; reuse for y
    #pragma unroll
    for (int r = 0; r < 16; ++r) {
        xs[r * DIM + c0] = acc0[r];
        xs[r * DIM + c1] = acc1[r];
    }
    __syncthreads();

    if (tid < 128) {            // one thread per (row, head)
        const int r = tid >> 3, h = tid & 7;
        const float* p = xs + r * DIM + h * HD;
        float s = 0.f, sq = 0.f;
        for (int j = 0; j < HD; ++j) { float v = p[j]; s += v; sq += v * v; }
        const float mean = s * (1.f / HD);
        const float var  = sq * (1.f / HD) - mean * mean;
        stat_m[tid] = mean;
        stat_r[tid] = rsqrtf(var + EPS);
    }
    __syncthreads();

    const float g0 = gamma[tid & 63], b0 = beta[tid & 63];   // (c0&63)==(c1&63)
    const int h0 = c0 >> 6, h1 = c1 >> 6;
    #pragma unroll
    for (int r = 0; r < 16; ++r) {
        const float m0 = stat_m[r * 8 + h0], rs0 = stat_r[r * 8 + h0];
        const float m1 = stat_m[r * 8 + h1], rs1 = stat_r[r * 8 + h1];
        float v0 = (xs[r * DIM + c0] - m0) * rs0 * g0 + b0;
        float v1 = (xs[r * DIM + c1] - m1) * rs1 * g0 + b0;
        if (MODE == 0) { v0 *= QSCALE; v1 *= QSCALE; }
        Y[(size_t)(row0 + r) * DIM + c0] = v0;
        Y[(size_t)(row0 + r) * DIM + c1] = v1;
    }
}

// ---------------------------------------------------------------------------
// attn_kernel: flash-style softmax(Q Kh^T) Vh per head.
// Block: 256 threads (4 waves), one head, 64 q-rows (16 per wave).
// Grid: 8 heads x 64 row-groups = 512 blocks (2/CU at 64 KB LDS).
// K chunk stored XOR-rotate swizzled ((j+n)&63) -> lane-row reads conflict-free
// with NO padding (keeps static LDS at exactly 65536 B).
// ---------------------------------------------------------------------------
__global__ __launch_bounds__(256) void attn_kernel(
    const float* __restrict__ Q, const float* __restrict__ K,
    const float* __restrict__ V, float* __restrict__ O)
{
    __shared__ __align__(16) float qs[64 * HD];      // 16 KB, plain layout
    __shared__ float ks[64 * HD];                    // 16 KB, swizzled
    __shared__ float vs[64 * HD];                    // 16 KB, plain
    __shared__ __align__(16) float ps[4 * 16 * 64];  // 16 KB, per-wave p
    const int tid  = threadIdx.x;
    const int w    = tid >> 6;
    const int lane = tid & 63;
    const int h    = blockIdx.x >> 6;    // 0..7 (head-major: L2 reuse of Kh/Vh)
    const int rg   = blockIdx.x & 63;
    const int row0 = rg * 64;

    for (int idx = tid; idx < 64 * HD / 4; idx += 256) {   // stage Q head-slice
        const int r = idx >> 4, jq = idx & 15;
        ((float4*)(qs + r * HD))[jq] =
            ((const float4*)(Q + (size_t)(row0 + r) * DIM + h * HD))[jq];
    }

    float m[16], s[16], o[16];
    #pragma unroll
    for (int r = 0; r < 16; ++r) { m[r] = -1.0e30f; s[r] = 0.f; o[r] = 0.f; }

    __syncthreads();

    for (int base = 0; base < NBANK; base += 64) {
        // stage K,V chunk (coalesced global reads)
        for (int idx = tid; idx < 64 * HD; idx += 256) {
            const int n = idx >> 6, j = idx & 63;
            ks[(n << 6) + ((j + n) & 63)] = K[(size_t)(base + n) * DIM + h * HD + j];
            vs[(n << 6) + j]              = V[(size_t)(base + n) * DIM + h * HD + j];
        }
        __syncthreads();

        // ---- scores: lane <-> n = base+lane ----
        float sc[16];
        #pragma unroll
        for (int r = 0; r < 16; ++r) sc[r] = 0.f;
        for (int j = 0; j < HD; j += 4) {
            const float k0 = ks[(lane << 6) + ((j + 0 + lane) & 63)];
            const float k1 = ks[(lane << 6) + ((j + 1 + lane) & 63)];
            const float k2 = ks[(lane << 6) + ((j + 2 + lane) & 63)];
            const float k3 = ks[(lane << 6) + ((j + 3 + lane) & 63)];
            #pragma unroll
            for (int r = 0; r < 16; ++r) {
                const float4 qv = *(const float4*)(qs + (w * 16 + r) * HD + j);
                sc[r] = fmaf(qv.x, k0, fmaf(qv.y, k1, fmaf(qv.z, k2, fmaf(qv.w, k3, sc[r]))));
            }
        }

        // ---- online softmax update, stage p per wave ----
        #pragma unroll
        for (int r = 0; r < 16; ++r) {
            float cm = sc[r];
            cm = fmaxf(cm, __shfl_xor(cm, 32));
            cm = fmaxf(cm, __shfl_xor(cm, 16));
            cm = fmaxf(cm, __shfl_xor(cm, 8));
            cm = fmaxf(cm, __shfl_xor(cm, 4));
            cm = fmaxf(cm, __shfl_xor(cm, 2));
            cm = fmaxf(cm, __shfl_xor(cm, 1));
            const float nm = fmaxf(m[r], cm);
            const float p  = __expf(sc[r] - nm);
            const float f  = __expf(m[r] - nm);
            float psum = p;
            psum += __shfl_xor(psum, 32);
            psum += __shfl_xor(psum, 16);
            psum += __shfl_xor(psum, 8);
            psum += __shfl_xor(psum, 4);
            psum += __shfl_xor(psum, 2);
            psum += __shfl_xor(psum, 1);
            s[r] = s[r] * f + psum;
            o[r] *= f;
            m[r] = nm;
            ps[((w * 16 + r) << 6) + lane] = p;
        }
        __syncthreads();

        // ---- PV: lane <-> output column ----
        for (int i = 0; i < 64; i += 4) {
            const float v0 = vs[((i + 0) << 6) + lane];
            const float v1 = vs[((i + 1) << 6) + lane];
            const float v2 = vs[((i + 2) << 6) + lane];
            const float v3 = vs[((i + 3) << 6) + lane];
            #pragma unroll
            for (int r = 0; r < 16; ++r) {
                const float4 pv = *(const float4*)(ps + ((w * 16 + r) << 6) + i);
                o[r] = fmaf(pv.x, v0, fmaf(pv.y, v1, fmaf(pv.z, v2, fmaf(pv.w, v3, o[r]))));
            }
        }
        __syncthreads();
    }

    #pragma unroll
    for (int r = 0; r < 16; ++r) {
        O[(size_t)(row0 + w * 16 + r) * DIM + h * HD + lane] = o[r] / s[r];
    }
}

// ---------------------------------------------------------------------------
// final_ln_proj_kernel: Y = LN_512(X) @ Wproj^T
// ---------------------------------------------------------------------------
__global__ __launch_bounds__(256) void final_ln_proj_kernel(
    const float* __restrict__ X, const float* __restrict__ W,
    const float* __restrict__ gamma, const float* __restrict__ beta,
    float* __restrict__ Y)
{
    __shared__ __align__(16) float xs[16 * DIM];
    __shared__ float red_s[256], red_q[256];
    __shared__ float stat_m[16], stat_r[16];
    const int tid  = threadIdx.x;
    const int row0 = blockIdx.x * 16;

    {
        const float4* src = (const float4*)(X + (size_t)row0 * DIM);
        float4* dst = (float4*)xs;
        for (int i = tid; i < 16 * DIM / 4; i += 256) dst[i] = src[i];
    }
    __syncthreads();

    {   // 16 threads per row, 32 elements each
        const int r = tid >> 4, seg = tid & 15;
        const float* p = xs + r * DIM + seg * 32;
        float s = 0.f, sq = 0.f;
        #pragma unroll
        for (int j = 0; j < 32; ++j) { float v = p[j]; s += v; sq += v * v; }
        red_s[tid] = s; red_q[tid] = sq;
    }
    __syncthreads();
    if (tid < 16) {
        float s = 0.f, sq = 0.f;
        for (int k = 0; k < 16; ++k) { s += red_s[tid * 16 + k]; sq += red_q[tid * 16 + k]; }
        const float mean = s * (1.f / DIM);
        const float var  = sq * (1.f / DIM) - mean * mean;
        stat_m[tid] = mean;
        stat_r[tid] = rsqrtf(var + EPS);
    }
    __syncthreads();

    for (int idx = tid; idx < 16 * DIM; idx += 256) {   // normalize in place
        const int r = idx >> 9, c = idx & 511;
        xs[idx] = (xs[idx] - stat_m[r]) * stat_r[r] * gamma[c] + beta[c];
    }
    __syncthreads();

    const int c0 = tid, c1 = tid + 256;
    float acc0[16], acc1[16];
    #pragma unroll
    for (int r = 0; r < 16; ++r) { acc0[r] = 0.f; acc1[r] = 0.f; }
    const float* w0 = W + (size_t)c0 * DIM;
    const float* w1 = W + (size_t)c1 * DIM;
    for (int k = 0; k < DIM; k += 4) {
        const float4 wv0 = *(const float4*)(w0 + k);
        const float4 wv1 = *(const float4*)(w1 + k);
        #pragma unroll
        for (int r = 0; r < 16; ++r) {
            const float4 xv = *(const float4*)(xs + r * DIM + k);
            acc0[r] = fmaf(xv.x, wv0.x, fmaf(xv.y, wv0.y, fmaf(xv.z, wv0.z, fmaf(xv.w, wv0.w, acc0[r]))));
            acc1[r] = fmaf(xv.x, wv1.x, fmaf(xv.y, wv1.y, fmaf(xv.z, wv1.z, fmaf(xv.w, wv1.w, acc1[r]))));
        }
    }
    #pragma unroll
    for (int r = 0; r < 16; ++r) {
        Y[(size_t)(row0 + r) * DIM + c0] = acc0[r];
        Y[(size_t)(row0 + r) * DIM + c1] = acc1[r];
    }
}

// ---------------------------------------------------------------------------
extern "C" void kernel_launch(void* const* d_in, const int* in_sizes, int n_in,
                              void* d_out, int out_size, void* d_ws, size_t ws_size,
                              hipStream_t stream)
{
    const float* x_q = (const float*)d_in[0];
    const float* x_k = (const float*)d_in[1];
    const float* x_v = (const float*)d_in[2];
    const float* Wq  = (const float*)d_in[3];
    const float* Wk  = (const float*)d_in[4];
    const float* Wv  = (const float*)d_in[5];
    const float* Wp  = (const float*)d_in[6];
    const float* qg  = (const float*)d_in[7];
    const float* qb  = (const float*)d_in[8];
    const float* kg  = (const float*)d_in[9];
    const float* kb  = (const float*)d_in[10];
    const float* ng  = (const float*)d_in[11];
    const float* nb  = (const float*)d_in[12];
    float* out = (float*)d_out;

    // workspace: Q | K | V | attn_out, 8 MB each (32 MB total)
    float* Qw = (float*)d_ws;
    float* Kw = Qw + (size_t)NQROWS * DIM;
    float* Vw = Kw + (size_t)NBANK * DIM;
    float* AO = Vw + (size_t)NBANK * DIM;

    proj_ln_kernel<0><<<NQROWS / 16, 256, 0, stream>>>(x_q, Wq, qg, qb, Qw);
    proj_ln_kernel<1><<<NBANK  / 16, 256, 0, stream>>>(x_k, Wk, kg, kb, Kw);
    proj_ln_kernel<2><<<NBANK  / 16, 256, 0, stream>>>(x_v, Wv, nullptr, nullptr, Vw);
    attn_kernel<<<NHEAD * 64, 256, 0, stream>>>(Qw, Kw, Vw, AO);
    final_ln_proj_kernel<<<NQROWS / 16, 256, 0, stream>>>(AO, Wp, ng, nb, out);
}

// Round 2
// 497.938 us; speedup vs baseline: 3.7360x; 3.7360x over previous
//
#include <hip/hip_runtime.h>
#include <math.h>

#define DIM 512
#define NHEAD 8
#define HD 64
#define NBANK 4096
#define NQROWS 4096
#define EPS 1e-5f
#define QSCALE 0.125f

typedef __attribute__((ext_vector_type(4))) float floatx4;
typedef __attribute__((ext_vector_type(8))) short short8;

__device__ __forceinline__ unsigned short f2bf(float f) {
    unsigned int u = __float_as_uint(f);
    u += 0x7fffu + ((u >> 16) & 1u);          // round-to-nearest-even
    return (unsigned short)(u >> 16);
}

// ---------------------------------------------------------------------------
// proj_ln_kernel: Y[row,o] = LN_head( sum_k X[row,k] * W[o,k] )  -> bf16 out
// MODE 0: per-head LN then * QSCALE, row-major bf16 (Q path)
// MODE 1: per-head LN, row-major bf16            (K path)
// MODE 2: plain GEMM, TRANSPOSED bf16 out VT[o][n] (V path; register tile is
//         already the transposed layout -> two short8 stores per column)
// ---------------------------------------------------------------------------
template<int MODE>
__global__ __launch_bounds__(256) void proj_ln_kernel(
    const float* __restrict__ X, const float* __restrict__ W,
    const float* __restrict__ gamma, const float* __restrict__ beta,
    unsigned short* __restrict__ Y)
{
    __shared__ __align__(16) float xs[16 * DIM];   // 32 KB
    __shared__ float stat_m[16 * NHEAD];
    __shared__ float stat_r[16 * NHEAD];
    const int tid  = threadIdx.x;
    const int row0 = blockIdx.x * 16;

    {   // stage 16 input rows, coalesced float4 (broadcast-reused by all lanes)
        const float4* src = (const float4*)(X + (size_t)row0 * DIM);
        float4* dst = (float4*)xs;
        for (int i = tid; i < 16 * DIM / 4; i += 256) dst[i] = src[i];
    }
    __syncthreads();

    const int c0 = tid, c1 = tid + 256;
    float acc0[16], acc1[16];
    #pragma unroll
    for (int r = 0; r < 16; ++r) { acc0[r] = 0.f; acc1[r] = 0.f; }

    const float* w0 = W + (size_t)c0 * DIM;
    const float* w1 = W + (size_t)c1 * DIM;
    for (int k = 0; k < DIM; k += 4) {
        const float4 wv0 = *(const float4*)(w0 + k);
        const float4 wv1 = *(const float4*)(w1 + k);
        #pragma unroll
        for (int r = 0; r < 16; ++r) {
            const float4 xv = *(const float4*)(xs + r * DIM + k);
            acc0[r] = fmaf(xv.x, wv0.x, fmaf(xv.y, wv0.y, fmaf(xv.z, wv0.z, fmaf(xv.w, wv0.w, acc0[r]))));
            acc1[r] = fmaf(xv.x, wv1.x, fmaf(xv.y, wv1.y, fmaf(xv.z, wv1.z, fmaf(xv.w, wv1.w, acc1[r]))));
        }
    }

    if (MODE == 2) {   // V path: acc0[r] = V[row0+r][c0]  ==  VT[c0][row0+r]
        short8 pa, pb, qa, qb;
        #pragma unroll
        for (int j = 0; j < 8; ++j) {
            pa[j] = (short)f2bf(acc0[j]);  pb[j] = (short)f2bf(acc0[j + 8]);
            qa[j] = (short)f2bf(acc1[j]);  qb[j] = (short)f2bf(acc1[j + 8]);
        }
        *(short8*)(Y + (size_t)c0 * NBANK + row0)     = pa;
        *(short8*)(Y + (size_t)c0 * NBANK + row0 + 8) = pb;
        *(short8*)(Y + (size_t)c1 * NBANK + row0)     = qa;
        *(short8*)(Y + (size_t)c1 * NBANK + row0 + 8) = qb;
        return;
    }

    __syncthreads();            // done reading xs as input; reuse for y
    #pragma unroll
    for (int r = 0; r < 16; ++r) {
        xs[r * DIM + c0] = acc0[r];
        xs[r * DIM + c1] = acc1[r];
    }
    __syncthreads();

    if (tid < 128) {            // one thread per (row, head)
        const int r = tid >> 3, hh = tid & 7;
        const float* p = xs + r * DIM + hh * HD;
        float s = 0.f, sq = 0.f;
        for (int j = 0; j < HD; ++j) { float v = p[j]; s += v; sq += v * v; }
        const float mean = s * (1.f / HD);
        const float var  = sq * (1.f / HD) - mean * mean;
        stat_m[tid] = mean;
        stat_r[tid] = rsqrtf(var + EPS);
    }
    __syncthreads();

    const float g0 = gamma[tid & 63], b0 = beta[tid & 63];
    const int h0 = c0 >> 6, h1 = c1 >> 6;
    #pragma unroll
    for (int r = 0; r < 16; ++r) {
        const float m0 = stat_m[r * 8 + h0], rs0 = stat_r[r * 8 + h0];
        const float m1 = stat_m[r * 8 + h1], rs1 = stat_r[r * 8 + h1];
        float v0 = (xs[r * DIM + c0] - m0) * rs0 * g0 + b0;
        float v1 = (xs[r * DIM + c1] - m1) * rs1 * g0 + b0;
        if (MODE == 0) { v0 *= QSCALE; v1 *= QSCALE; }
        Y[(size_t)(row0 + r) * DIM + c0] = f2bf(v0);
        Y[(size_t)(row0 + r) * DIM + c1] = f2bf(v1);
    }
}

// ---------------------------------------------------------------------------
// attn_kernel: MFMA-bf16 flash attention, no-max softmax (scores ~N(0,1),
// fp32 exp cannot overflow).  Block = 1 head x 64 q-rows, 4 waves x 16 rows.
// LDS tiles use 16B-block XOR swizzle -> all ds_read_b128 conflict-free.
// ---------------------------------------------------------------------------
__global__ __launch_bounds__(256) void attn_kernel(
    const unsigned short* __restrict__ Qb, const unsigned short* __restrict__ Kb,
    const unsigned short* __restrict__ VTb, float* __restrict__ AO)
{
    __shared__ short8 ks [512];   // 8 KB  K chunk  [n][hd]  swizzled
    __shared__ short8 vts[512];   // 8 KB  V^T chunk [hd][n] swizzled
    __shared__ short8 ps [512];   // 8 KB  P, per-wave [16][64] swizzled
    const int tid  = threadIdx.x;
    const int w    = tid >> 6;
    const int lane = tid & 63;
    const int m    = lane & 15;      // fragment row / col index
    const int q    = lane >> 4;      // quad
    const int h    = blockIdx.x & 7;            // head == XCD (L2 locality)
    const int row0 = (blockIdx.x >> 3) * 64;

    // Q fragments: A[m][k=q*8+j], hoisted out of the n-loop (2 frags = 8 VGPR)
    short8 qf[2];
    #pragma unroll
    for (int s = 0; s < 2; ++s)
        qf[s] = *(const short8*)(Qb + (size_t)(row0 + w * 16 + m) * DIM + h * HD + s * 32 + q * 8);

    floatx4 of[4];
    float sump[4];
    #pragma unroll
    for (int t = 0; t < 4; ++t) of[t] = (floatx4){0.f, 0.f, 0.f, 0.f};
    #pragma unroll
    for (int r = 0; r < 4; ++r) sump[r] = 0.f;

    unsigned short* psu = (unsigned short*)ps;

    for (int base = 0; base < NBANK; base += 64) {
        __syncthreads();                       // prior chunk reads complete
        #pragma unroll
        for (int it = 0; it < 2; ++it) {       // stage K + V^T chunk (bf16)
            const int idx = tid + it * 256;
            const int n = idx >> 3, seg = idx & 7, sw = seg ^ (n & 7);
            ks [n * 8 + sw] = *(const short8*)(Kb  + (size_t)(base + n) * DIM  + h * HD + seg * 8);
            vts[n * 8 + sw] = *(const short8*)(VTb + (size_t)(h * HD + n) * NBANK + base + seg * 8);
        }
        __syncthreads();

        // ---- S = Q K^T : 4 n-tiles x 2 k-steps ----
        floatx4 sc[4];
        #pragma unroll
        for (int t = 0; t < 4; ++t) sc[t] = (floatx4){0.f, 0.f, 0.f, 0.f};
        #pragma unroll
        for (int s = 0; s < 2; ++s) {
            #pragma unroll
            for (int t = 0; t < 4; ++t) {
                const short8 kf = ks[(t * 16 + m) * 8 + ((s * 4 + q) ^ (m & 7))];
                sc[t] = __builtin_amdgcn_mfma_f32_16x16x32_bf16(qf[s], kf, sc[t], 0, 0, 0);
            }
        }

        // ---- P = exp(S); accumulate per-lane row-sum partials; stage P ----
        #pragma unroll
        for (int t = 0; t < 4; ++t) {
            #pragma unroll
            for (int r = 0; r < 4; ++r) {
                const float p = __expf(sc[t][r]);
                sump[r] += p;
                const int row  = q * 4 + r;             // C-layout row
                const int colb = t * 2 + (m >> 3);      // 16B block of col
                psu[(w * 16 + row) * 64 + ((colb ^ (row & 7)) * 8) + (m & 7)] = f2bf(p);
            }
        }

        // ---- O += P V : P via LDS round-trip into A-layout ----
        short8 pf[2];
        #pragma unroll
        for (int s = 0; s < 2; ++s)
            pf[s] = ps[(w * 16 + m) * 8 + ((s * 4 + q) ^ (m & 7))];
        #pragma unroll
        for (int s = 0; s < 2; ++s) {
            #pragma unroll
            for (int t = 0; t < 4; ++t) {
                const short8 vf = vts[(t * 16 + m) * 8 + ((s * 4 + q) ^ (m & 7))];
                of[t] = __builtin_amdgcn_mfma_f32_16x16x32_bf16(pf[s], vf, of[t], 0, 0, 0);
            }
        }
    }

    // ---- epilogue: one shuffle reduction for denominators, store O ----
    #pragma unroll
    for (int r = 0; r < 4; ++r) {
        float s = sump[r];
        s += __shfl_xor(s, 1); s += __shfl_xor(s, 2);
        s += __shfl_xor(s, 4); s += __shfl_xor(s, 8);
        sump[r] = 1.0f / s;
    }
    #pragma unroll
    for (int t = 0; t < 4; ++t) {
        #pragma unroll
        for (int r = 0; r < 4; ++r) {
            AO[(size_t)(row0 + w * 16 + q * 4 + r) * DIM + h * HD + t * 16 + m] = of[t][r] * sump[r];
        }
    }
}

// ---------------------------------------------------------------------------
// final_ln_proj_kernel: Y = LN_512(X) @ Wproj^T   (fp32)
// ---------------------------------------------------------------------------
__global__ __launch_bounds__(256) void final_ln_proj_kernel(
    const float* __restrict__ X, const float* __restrict__ W,
    const float* __restrict__ gamma, const float* __restrict__ beta,
    float* __restrict__ Y)
{
    __shared__ __align__(16) float xs[16 * DIM];
    __shared__ float red_s[256], red_q[256];
    __shared__ float stat_m[16], stat_r[16];
    const int tid  = threadIdx.x;
    const int row0 = blockIdx.x * 16;

    {
        const float4* src = (const float4*)(X + (size_t)row0 * DIM);
        float4* dst = (float4*)xs;
        for (int i = tid; i < 16 * DIM / 4; i += 256) dst[i] = src[i];
    }
    __syncthreads();

    {
        const int r = tid >> 4, seg = tid & 15;
        const float* p = xs + r * DIM + seg * 32;
        float s = 0.f, sq = 0.f;
        #pragma unroll
        for (int j = 0; j < 32; ++j) { float v = p[j]; s += v; sq += v * v; }
        red_s[tid] = s; red_q[tid] = sq;
    }
    __syncthreads();
    if (tid < 16) {
        float s = 0.f, sq = 0.f;
        for (int k = 0; k < 16; ++k) { s += red_s[tid * 16 + k]; sq += red_q[tid * 16 + k]; }
        const float mean = s * (1.f / DIM);
        const float var  = sq * (1.f / DIM) - mean * mean;
        stat_m[tid] = mean;
        stat_r[tid] = rsqrtf(var + EPS);
    }
    __syncthreads();

    for (int idx = tid; idx < 16 * DIM; idx += 256) {
        const int r = idx >> 9, c = idx & 511;
        xs[idx] = (xs[idx] - stat_m[r]) * stat_r[r] * gamma[c] + beta[c];
    }
    __syncthreads();

    const int c0 = tid, c1 = tid + 256;
    float acc0[16], acc1[16];
    #pragma unroll
    for (int r = 0; r < 16; ++r) { acc0[r] = 0.f; acc1[r] = 0.f; }
    const float* w0 = W + (size_t)c0 * DIM;
    const float* w1 = W + (size_t)c1 * DIM;
    for (int k = 0; k < DIM; k += 4) {
        const float4 wv0 = *(const float4*)(w0 + k);
        const float4 wv1 = *(const float4*)(w1 + k);
        #pragma unroll
        for (int r = 0; r < 16; ++r) {
            const float4 xv = *(const float4*)(xs + r * DIM + k);
            acc0[r] = fmaf(xv.x, wv0.x, fmaf(xv.y, wv0.y, fmaf(xv.z, wv0.z, fmaf(xv.w, wv0.w, acc0[r]))));
            acc1[r] = fmaf(xv.x, wv1.x, fmaf(xv.y, wv1.y, fmaf(xv.z, wv1.z, fmaf(xv.w, wv1.w, acc1[r]))));
        }
    }
    #pragma unroll
    for (int r = 0; r < 16; ++r) {
        Y[(size_t)(row0 + r) * DIM + c0] = acc0[r];
        Y[(size_t)(row0 + r) * DIM + c1] = acc1[r];
    }
}

// ---------------------------------------------------------------------------
extern "C" void kernel_launch(void* const* d_in, const int* in_sizes, int n_in,
                              void* d_out, int out_size, void* d_ws, size_t ws_size,
                              hipStream_t stream)
{
    const float* x_q = (const float*)d_in[0];
    const float* x_k = (const float*)d_in[1];
    const float* x_v = (const float*)d_in[2];
    const float* Wq  = (const float*)d_in[3];
    const float* Wk  = (const float*)d_in[4];
    const float* Wv  = (const float*)d_in[5];
    const float* Wp  = (const float*)d_in[6];
    const float* qg  = (const float*)d_in[7];
    const float* qb  = (const float*)d_in[8];
    const float* kg  = (const float*)d_in[9];
    const float* kb  = (const float*)d_in[10];
    const float* ng  = (const float*)d_in[11];
    const float* nb  = (const float*)d_in[12];
    float* out = (float*)d_out;

    // workspace: Qb | Kb | VTb (bf16, 4 MB each) | AO (fp32, 8 MB)
    unsigned short* Qb  = (unsigned short*)d_ws;
    unsigned short* Kb  = Qb  + (size_t)NQROWS * DIM;
    unsigned short* VTb = Kb  + (size_t)NBANK * DIM;
    float*          AO  = (float*)(VTb + (size_t)NBANK * DIM);

    proj_ln_kernel<0><<<NQROWS / 16, 256, 0, stream>>>(x_q, Wq, qg, qb, Qb);
    proj_ln_kernel<1><<<NBANK  / 16, 256, 0, stream>>>(x_k, Wk, kg, kb, Kb);
    proj_ln_kernel<2><<<NBANK  / 16, 256, 0, stream>>>(x_v, Wv, nullptr, nullptr, VTb);
    attn_kernel<<<NHEAD * 64, 256, 0, stream>>>(Qb, Kb, VTb, AO);
    final_ln_proj_kernel<<<NQROWS / 16, 256, 0, stream>>>(AO, Wp, ng, nb, out);
}

// Round 3
// 229.055 us; speedup vs baseline: 8.1217x; 2.1739x over previous
//
#include <hip/hip_runtime.h>
#include <hip/hip_bf16.h>
#include <math.h>

#define DIM 512
#define NHEAD 8
#define HD 64
#define NBANK 4096
#define NQROWS 4096
#define EPS 1e-5f
#define QSCALE 0.125f

typedef __attribute__((ext_vector_type(4))) float floatx4;
typedef __attribute__((ext_vector_type(8))) short short8;

__device__ __forceinline__ unsigned short f2bf(float f) {
    unsigned int u = __float_as_uint(f);
    u += 0x7fffu + ((u >> 16) & 1u);          // round-to-nearest-even
    return (unsigned short)(u >> 16);
}

// packed fp32x2 -> bf16x2 (v_cvt_pk_bf16_f32), low short = a
__device__ __forceinline__ unsigned int pk2(float a, float b) {
    union { __hip_bfloat162 h; unsigned int u; } cvt;
    cvt.h = __float22bfloat162_rn(make_float2(a, b));
    return cvt.u;
}

// ---------------------------------------------------------------------------
// qkv_kernel: fused bf16-MFMA projections.
// grid (32, 12): x = row-tile (128 rows), y: [0,4)=Q, [4,8)=K, [8,12)=V col-tile.
// Block 256 thr = 4 waves, each wave one 64x64 subtile (4x4 mfma_16x16x32_bf16).
// Staging converts fp32 global -> bf16 LDS (packed cvt). XOR-seg swizzle ->
// conflict-free ds_read_b128 fragment loads.
// Epilogue: Q/K per-head LN in registers (quad shuffles), row-major bf16 out.
//           V transposed via LDS (pad 136) -> coalesced VT bf16 out.
// ---------------------------------------------------------------------------
__global__ __launch_bounds__(256) void qkv_kernel(
    const float* __restrict__ xq, const float* __restrict__ xk, const float* __restrict__ xv,
    const float* __restrict__ Wqp, const float* __restrict__ Wkp, const float* __restrict__ Wvp,
    const float* __restrict__ qg, const float* __restrict__ qbeta,
    const float* __restrict__ kg, const float* __restrict__ kbeta,
    unsigned short* __restrict__ Qb, unsigned short* __restrict__ Kb,
    unsigned short* __restrict__ VTb)
{
    __shared__ short8 smem[2176];   // 34816 B: A tile [0,1024), B tile [1024,2048); epilogue VT
    short8* as = smem;
    short8* bsx = smem + 1024;
    const int tid  = threadIdx.x;
    const int w    = tid >> 6, lane = tid & 63, m = lane & 15, q = lane >> 4;
    const int wr   = w >> 1, wc = w & 1;
    const int row0 = blockIdx.x * 128;
    const int mat  = blockIdx.y >> 2;
    const int col0 = (blockIdx.y & 3) * 128;
    const float* X = (mat == 0) ? xq : (mat == 1) ? xk : xv;
    const float* W = (mat == 0) ? Wqp : (mat == 1) ? Wkp : Wvp;

    floatx4 acc[4][4];
    #pragma unroll
    for (int mt = 0; mt < 4; ++mt)
        #pragma unroll
        for (int nt = 0; nt < 4; ++nt) acc[mt][nt] = (floatx4){0.f, 0.f, 0.f, 0.f};

    for (int k0 = 0; k0 < DIM; k0 += 64) {
        #pragma unroll
        for (int p = 0; p < 4; ++p) {          // stage A(128x64) + B(128x64)
            const int idx = tid + p * 256;
            const int row = idx >> 3, seg = idx & 7;
            const float4* pa = (const float4*)(X + (size_t)(row0 + row) * DIM + k0 + seg * 8);
            const float4* pb = (const float4*)(W + (size_t)(col0 + row) * DIM + k0 + seg * 8);
            const float4 a0 = pa[0], a1 = pa[1];
            const float4 b0 = pb[0], b1 = pb[1];
            union { short8 v; unsigned int u[4]; } ta, tb;
            ta.u[0] = pk2(a0.x, a0.y); ta.u[1] = pk2(a0.z, a0.w);
            ta.u[2] = pk2(a1.x, a1.y); ta.u[3] = pk2(a1.z, a1.w);
            tb.u[0] = pk2(b0.x, b0.y); tb.u[1] = pk2(b0.z, b0.w);
            tb.u[2] = pk2(b1.x, b1.y); tb.u[3] = pk2(b1.z, b1.w);
            as [row * 8 + (seg ^ (row & 7))] = ta.v;
            bsx[row * 8 + (seg ^ (row & 7))] = tb.v;
        }
        __syncthreads();
        #pragma unroll
        for (int s = 0; s < 2; ++s) {
            short8 af[4], bfr[4];
            #pragma unroll
            for (int mt = 0; mt < 4; ++mt)
                af[mt] = as[(wr * 64 + mt * 16 + m) * 8 + ((s * 4 + q) ^ (m & 7))];
            #pragma unroll
            for (int nt = 0; nt < 4; ++nt)
                bfr[nt] = bsx[(wc * 64 + nt * 16 + m) * 8 + ((s * 4 + q) ^ (m & 7))];
            #pragma unroll
            for (int mt = 0; mt < 4; ++mt)
                #pragma unroll
                for (int nt = 0; nt < 4; ++nt)
                    acc[mt][nt] = __builtin_amdgcn_mfma_f32_16x16x32_bf16(af[mt], bfr[nt], acc[mt][nt], 0, 0, 0);
        }
        __syncthreads();
    }

    if (mat < 2) {
        // per-head LN: wave's 64-col span == one head; stats via regs + quad shuffles
        const float* g = (mat == 0) ? qg : kg;
        const float* be = (mat == 0) ? qbeta : kbeta;
        unsigned short* Y = (mat == 0) ? Qb : Kb;
        float gv[4], bv[4];
        #pragma unroll
        for (int nt = 0; nt < 4; ++nt) { gv[nt] = g[nt * 16 + m]; bv[nt] = be[nt * 16 + m]; }
        #pragma unroll
        for (int mt = 0; mt < 4; ++mt) {
            #pragma unroll
            for (int r = 0; r < 4; ++r) {
                float s = 0.f, sq = 0.f;
                #pragma unroll
                for (int nt = 0; nt < 4; ++nt) { const float v = acc[mt][nt][r]; s += v; sq += v * v; }
                s  += __shfl_xor(s, 1);  s  += __shfl_xor(s, 2);  s  += __shfl_xor(s, 4);  s  += __shfl_xor(s, 8);
                sq += __shfl_xor(sq, 1); sq += __shfl_xor(sq, 2); sq += __shfl_xor(sq, 4); sq += __shfl_xor(sq, 8);
                const float mean = s * (1.f / HD);
                const float var  = sq * (1.f / HD) - mean * mean;
                const float rr   = rsqrtf(var + EPS);
                const int grow = row0 + wr * 64 + mt * 16 + q * 4 + r;
                #pragma unroll
                for (int nt = 0; nt < 4; ++nt) {
                    float v = (acc[mt][nt][r] - mean) * rr * gv[nt] + bv[nt];
                    if (mat == 0) v *= QSCALE;
                    Y[(size_t)grow * DIM + col0 + wc * 64 + nt * 16 + m] = f2bf(v);
                }
            }
        }
    } else {
        // V: transpose via LDS (row stride 136 shorts), coalesced VT store
        unsigned short* vt = (unsigned short*)smem;
        #pragma unroll
        for (int mt = 0; mt < 4; ++mt)
            #pragma unroll
            for (int nt = 0; nt < 4; ++nt) {
                const int c  = wc * 64 + nt * 16 + m;
                const int rw = wr * 64 + mt * 16 + q * 4;
                *(unsigned int*)(vt + c * 136 + rw)     = pk2(acc[mt][nt][0], acc[mt][nt][1]);
                *(unsigned int*)(vt + c * 136 + rw + 2) = pk2(acc[mt][nt][2], acc[mt][nt][3]);
            }
        __syncthreads();
        #pragma unroll
        for (int p = 0; p < 8; ++p) {
            const int idx = tid + p * 256;      // 2048 short8 = 128 cols x 16
            const int c = idx >> 4, sg = idx & 15;
            *(short8*)(VTb + (size_t)(col0 + c) * NBANK + row0 + sg * 8) =
                *(const short8*)(vt + c * 136 + sg * 8);
        }
    }
}

// ---------------------------------------------------------------------------
// attn_kernel: MFMA-bf16 flash attention, no-max softmax (scores ~N(0,1),
// fp32 exp cannot overflow).  Block = 1 head x 64 q-rows, 4 waves x 16 rows.
// ---------------------------------------------------------------------------
__global__ __launch_bounds__(256) void attn_kernel(
    const unsigned short* __restrict__ Qb, const unsigned short* __restrict__ Kb,
    const unsigned short* __restrict__ VTb, float* __restrict__ AO)
{
    __shared__ short8 ks [512];   // 8 KB  K chunk  [n][hd]  swizzled
    __shared__ short8 vts[512];   // 8 KB  V^T chunk [hd][n] swizzled
    __shared__ short8 ps [512];   // 8 KB  P, per-wave [16][64] swizzled
    const int tid  = threadIdx.x;
    const int w    = tid >> 6;
    const int lane = tid & 63;
    const int m    = lane & 15;
    const int q    = lane >> 4;
    const int h    = blockIdx.x & 7;
    const int row0 = (blockIdx.x >> 3) * 64;

    short8 qf[2];
    #pragma unroll
    for (int s = 0; s < 2; ++s)
        qf[s] = *(const short8*)(Qb + (size_t)(row0 + w * 16 + m) * DIM + h * HD + s * 32 + q * 8);

    floatx4 of[4];
    float sump[4];
    #pragma unroll
    for (int t = 0; t < 4; ++t) of[t] = (floatx4){0.f, 0.f, 0.f, 0.f};
    #pragma unroll
    for (int r = 0; r < 4; ++r) sump[r] = 0.f;

    unsigned short* psu = (unsigned short*)ps;

    for (int base = 0; base < NBANK; base += 64) {
        __syncthreads();
        #pragma unroll
        for (int it = 0; it < 2; ++it) {
            const int idx = tid + it * 256;
            const int n = idx >> 3, seg = idx & 7, sw = seg ^ (n & 7);
            ks [n * 8 + sw] = *(const short8*)(Kb  + (size_t)(base + n) * DIM  + h * HD + seg * 8);
            vts[n * 8 + sw] = *(const short8*)(VTb + (size_t)(h * HD + n) * NBANK + base + seg * 8);
        }
        __syncthreads();

        floatx4 sc[4];
        #pragma unroll
        for (int t = 0; t < 4; ++t) sc[t] = (floatx4){0.f, 0.f, 0.f, 0.f};
        #pragma unroll
        for (int s = 0; s < 2; ++s) {
            #pragma unroll
            for (int t = 0; t < 4; ++t) {
                const short8 kf = ks[(t * 16 + m) * 8 + ((s * 4 + q) ^ (m & 7))];
                sc[t] = __builtin_amdgcn_mfma_f32_16x16x32_bf16(qf[s], kf, sc[t], 0, 0, 0);
            }
        }

        #pragma unroll
        for (int t = 0; t < 4; ++t) {
            #pragma unroll
            for (int r = 0; r < 4; ++r) {
                const float p = __expf(sc[t][r]);
                sump[r] += p;
                const int row  = q * 4 + r;
                const int colb = t * 2 + (m >> 3);
                psu[(w * 16 + row) * 64 + ((colb ^ (row & 7)) * 8) + (m & 7)] = f2bf(p);
            }
        }

        short8 pf[2];
        #pragma unroll
        for (int s = 0; s < 2; ++s)
            pf[s] = ps[(w * 16 + m) * 8 + ((s * 4 + q) ^ (m & 7))];
        #pragma unroll
        for (int s = 0; s < 2; ++s) {
            #pragma unroll
            for (int t = 0; t < 4; ++t) {
                const short8 vf = vts[(t * 16 + m) * 8 + ((s * 4 + q) ^ (m & 7))];
                of[t] = __builtin_amdgcn_mfma_f32_16x16x32_bf16(pf[s], vf, of[t], 0, 0, 0);
            }
        }
    }

    #pragma unroll
    for (int r = 0; r < 4; ++r) {
        float s = sump[r];
        s += __shfl_xor(s, 1); s += __shfl_xor(s, 2);
        s += __shfl_xor(s, 4); s += __shfl_xor(s, 8);
        sump[r] = 1.0f / s;
    }
    #pragma unroll
    for (int t = 0; t < 4; ++t) {
        #pragma unroll
        for (int r = 0; r < 4; ++r) {
            AO[(size_t)(row0 + w * 16 + q * 4 + r) * DIM + h * HD + t * 16 + m] = of[t][r] * sump[r];
        }
    }
}

// ---------------------------------------------------------------------------
// final_kernel: out = LN_512(AO) @ Wproj^T, LN fused into A staging.
// grid (64, 4): 64-row x 128-col tiles, 128 thr = 2 waves (wave = 64-col half).
// Stats pre-pass reads the block's 64 rows (L2-hot), then k-loop stages
// normalized bf16 A + bf16 W, MFMA core identical to qkv_kernel.
// ---------------------------------------------------------------------------
__global__ __launch_bounds__(128) void final_kernel(
    const float* __restrict__ AO, const float* __restrict__ W,
    const float* __restrict__ g, const float* __restrict__ be,
    float* __restrict__ out)
{
    __shared__ short8 fsmem[1536];          // A: [0,512) = 64x64, B: [512,1536) = 128x64
    __shared__ float sm[64], sr[64], redS[128], redQ[128];
    __shared__ float gls[512], bls[512];
    const int tid  = threadIdx.x;
    const int w    = tid >> 6, lane = tid & 63, m = lane & 15, q = lane >> 4;
    const int row0 = blockIdx.x * 64;
    const int col0 = blockIdx.y * 128;

    for (int i = tid; i < 512; i += 128) { gls[i] = g[i]; bls[i] = be[i]; }

    {   // stats pre-pass: 2 threads per row, 256 floats each
        const int row = tid >> 1, half = tid & 1;
        const float4* pp = (const float4*)(AO + (size_t)(row0 + row) * DIM + half * 256);
        float s = 0.f, sq = 0.f;
        #pragma unroll
        for (int j = 0; j < 64; ++j) {
            const float4 v = pp[j];
            s  += v.x + v.y + v.z + v.w;
            sq += v.x * v.x + v.y * v.y + v.z * v.z + v.w * v.w;
        }
        redS[tid] = s; redQ[tid] = sq;
    }
    __syncthreads();
    if (tid < 64) {
        const float s  = redS[2 * tid] + redS[2 * tid + 1];
        const float sq = redQ[2 * tid] + redQ[2 * tid + 1];
        const float mean = s * (1.f / DIM);
        const float var  = sq * (1.f / DIM) - mean * mean;
        sm[tid] = mean;
        sr[tid] = rsqrtf(var + EPS);
    }
    __syncthreads();

    floatx4 acc[4][4];
    #pragma unroll
    for (int mt = 0; mt < 4; ++mt)
        #pragma unroll
        for (int nt = 0; nt < 4; ++nt) acc[mt][nt] = (floatx4){0.f, 0.f, 0.f, 0.f};

    for (int k0 = 0; k0 < DIM; k0 += 64) {
        #pragma unroll
        for (int p = 0; p < 12; ++p) {       // items: [0,512)=A rows, [512,1536)=B rows
            const int idx = tid + p * 128;
            if (idx < 512) {
                const int row = idx >> 3, seg = idx & 7;
                const float4* pa = (const float4*)(AO + (size_t)(row0 + row) * DIM + k0 + seg * 8);
                const float4 a0 = pa[0], a1 = pa[1];
                const float mm = sm[row], rr = sr[row];
                const float* gp = gls + k0 + seg * 8;
                const float* bp = bls + k0 + seg * 8;
                const float v0 = (a0.x - mm) * rr * gp[0] + bp[0];
                const float v1 = (a0.y - mm) * rr * gp[1] + bp[1];
                const float v2 = (a0.z - mm) * rr * gp[2] + bp[2];
                const float v3 = (a0.w - mm) * rr * gp[3] + bp[3];
                const float v4 = (a1.x - mm) * rr * gp[4] + bp[4];
                const float v5 = (a1.y - mm) * rr * gp[5] + bp[5];
                const float v6 = (a1.z - mm) * rr * gp[6] + bp[6];
                const float v7 = (a1.w - mm) * rr * gp[7] + bp[7];
                union { short8 v; unsigned int u[4]; } ta;
                ta.u[0] = pk2(v0, v1); ta.u[1] = pk2(v2, v3);
                ta.u[2] = pk2(v4, v5); ta.u[3] = pk2(v6, v7);
                fsmem[row * 8 + (seg ^ (row & 7))] = ta.v;
            } else {
                const int j = idx - 512;
                const int row = j >> 3, seg = j & 7;
                const float4* pb = (const float4*)(W + (size_t)(col0 + row) * DIM + k0 + seg * 8);
                const float4 b0 = pb[0], b1 = pb[1];
                union { short8 v; unsigned int u[4]; } tb;
                tb.u[0] = pk2(b0.x, b0.y); tb.u[1] = pk2(b0.z, b0.w);
                tb.u[2] = pk2(b1.x, b1.y); tb.u[3] = pk2(b1.z, b1.w);
                fsmem[512 + row * 8 + (seg ^ (row & 7))] = tb.v;
            }
        }
        __syncthreads();
        #pragma unroll
        for (int s = 0; s < 2; ++s) {
            short8 af[4], bfr[4];
            #pragma unroll
            for (int mt = 0; mt < 4; ++mt)
                af[mt] = fsmem[(mt * 16 + m) * 8 + ((s * 4 + q) ^ (m & 7))];
            #pragma unroll
            for (int nt = 0; nt < 4; ++nt)
                bfr[nt] = fsmem[512 + (w * 64 + nt * 16 + m) * 8 + ((s * 4 + q) ^ (m & 7))];
            #pragma unroll
            for (int mt = 0; mt < 4; ++mt)
                #pragma unroll
                for (int nt = 0; nt < 4; ++nt)
                    acc[mt][nt] = __builtin_amdgcn_mfma_f32_16x16x32_bf16(af[mt], bfr[nt], acc[mt][nt], 0, 0, 0);
        }
        __syncthreads();
    }

    #pragma unroll
    for (int mt = 0; mt < 4; ++mt)
        #pragma unroll
        for (int r = 0; r < 4; ++r)
            #pragma unroll
            for (int nt = 0; nt < 4; ++nt)
                out[(size_t)(row0 + mt * 16 + q * 4 + r) * DIM + col0 + w * 64 + nt * 16 + m] = acc[mt][nt][r];
}

// ---------------------------------------------------------------------------
extern "C" void kernel_launch(void* const* d_in, const int* in_sizes, int n_in,
                              void* d_out, int out_size, void* d_ws, size_t ws_size,
                              hipStream_t stream)
{
    const float* x_q = (const float*)d_in[0];
    const float* x_k = (const float*)d_in[1];
    const float* x_v = (const float*)d_in[2];
    const float* Wq  = (const float*)d_in[3];
    const float* Wk  = (const float*)d_in[4];
    const float* Wv  = (const float*)d_in[5];
    const float* Wp  = (const float*)d_in[6];
    const float* qg  = (const float*)d_in[7];
    const float* qb  = (const float*)d_in[8];
    const float* kg  = (const float*)d_in[9];
    const float* kb  = (const float*)d_in[10];
    const float* ng  = (const float*)d_in[11];
    const float* nb  = (const float*)d_in[12];
    float* out = (float*)d_out;

    // workspace: Qb | Kb | VTb (bf16, 4 MB each) | AO (fp32, 8 MB)
    unsigned short* Qb  = (unsigned short*)d_ws;
    unsigned short* Kb  = Qb  + (size_t)NQROWS * DIM;
    unsigned short* VTb = Kb  + (size_t)NBANK * DIM;
    float*          AO  = (float*)(VTb + (size_t)NBANK * DIM);

    qkv_kernel<<<dim3(32, 12), 256, 0, stream>>>(x_q, x_k, x_v, Wq, Wk, Wv,
                                                 qg, qb, kg, kb, Qb, Kb, VTb);
    attn_kernel<<<NHEAD * 64, 256, 0, stream>>>(Qb, Kb, VTb, AO);
    final_kernel<<<dim3(64, 4), 128, 0, stream>>>(AO, Wp, ng, nb, out);
}

// Round 4
// 193.975 us; speedup vs baseline: 9.5905x; 1.1808x over previous
//
#include <hip/hip_runtime.h>
#include <hip/hip_bf16.h>
#include <math.h>

#define DIM 512
#define NHEAD 8
#define HD 64
#define NBANK 4096
#define NQROWS 4096
#define EPS 1e-5f
#define QSCALE 0.125f
#define PART_ELEMS (NQROWS * DIM)   // one O-partial buffer (bf16 elems)

typedef __attribute__((ext_vector_type(4))) float floatx4;
typedef __attribute__((ext_vector_type(8))) short short8;

__device__ __forceinline__ unsigned short f2bf(float f) {
    unsigned int u = __float_as_uint(f);
    u += 0x7fffu + ((u >> 16) & 1u);          // round-to-nearest-even
    return (unsigned short)(u >> 16);
}
__device__ __forceinline__ float bf2f(unsigned short h) {
    return __uint_as_float(((unsigned int)h) << 16);
}
// packed fp32x2 -> bf16x2, low short = a
__device__ __forceinline__ unsigned int pk2(float a, float b) {
    union { __hip_bfloat162 h; unsigned int u; } cvt;
    cvt.h = __float22bfloat162_rn(make_float2(a, b));
    return cvt.u;
}

// ---------------------------------------------------------------------------
// qkv_kernel: fused bf16-MFMA projections, 64x128 tiles for occupancy.
// grid (64, 12): x = row-tile (64 rows), y: [0,4)=Q, [4,8)=K, [8,12)=V col-tile.
// 256 thr = 4 waves: wr=w&1 (32-row half), wc=w>>1 (64-col half); acc 2x4.
// ---------------------------------------------------------------------------
__global__ __launch_bounds__(256) void qkv_kernel(
    const float* __restrict__ xq, const float* __restrict__ xk, const float* __restrict__ xv,
    const float* __restrict__ Wqp, const float* __restrict__ Wkp, const float* __restrict__ Wvp,
    const float* __restrict__ qg, const float* __restrict__ qbeta,
    const float* __restrict__ kg, const float* __restrict__ kbeta,
    unsigned short* __restrict__ Qb, unsigned short* __restrict__ Kb,
    unsigned short* __restrict__ VTb)
{
    __shared__ short8 smem[1536];   // A [0,512)=64x64, B [512,1536)=128x64 (24 KB)
    short8* as = smem;
    short8* bs = smem + 512;
    const int tid  = threadIdx.x;
    const int w    = tid >> 6, lane = tid & 63, m = lane & 15, q = lane >> 4;
    const int wr   = w & 1, wc = w >> 1;
    const int row0 = blockIdx.x * 64;
    const int mat  = blockIdx.y >> 2;
    const int col0 = (blockIdx.y & 3) * 128;
    const float* X = (mat == 0) ? xq : (mat == 1) ? xk : xv;
    const float* W = (mat == 0) ? Wqp : (mat == 1) ? Wkp : Wvp;

    floatx4 acc[2][4];
    #pragma unroll
    for (int mt = 0; mt < 2; ++mt)
        #pragma unroll
        for (int nt = 0; nt < 4; ++nt) acc[mt][nt] = (floatx4){0.f, 0.f, 0.f, 0.f};

    for (int k0 = 0; k0 < DIM; k0 += 64) {
        #pragma unroll
        for (int p = 0; p < 6; ++p) {     // 512 A items + 1024 B items
            const int idx = tid + p * 256;
            if (idx < 512) {
                const int row = idx >> 3, seg = idx & 7;
                const float4* pa = (const float4*)(X + (size_t)(row0 + row) * DIM + k0 + seg * 8);
                const float4 a0 = pa[0], a1 = pa[1];
                union { short8 v; unsigned int u[4]; } ta;
                ta.u[0] = pk2(a0.x, a0.y); ta.u[1] = pk2(a0.z, a0.w);
                ta.u[2] = pk2(a1.x, a1.y); ta.u[3] = pk2(a1.z, a1.w);
                as[row * 8 + (seg ^ (row & 7))] = ta.v;
            } else {
                const int j = idx - 512;
                const int row = j >> 3, seg = j & 7;
                const float4* pb = (const float4*)(W + (size_t)(col0 + row) * DIM + k0 + seg * 8);
                const float4 b0 = pb[0], b1 = pb[1];
                union { short8 v; unsigned int u[4]; } tb;
                tb.u[0] = pk2(b0.x, b0.y); tb.u[1] = pk2(b0.z, b0.w);
                tb.u[2] = pk2(b1.x, b1.y); tb.u[3] = pk2(b1.z, b1.w);
                bs[row * 8 + (seg ^ (row & 7))] = tb.v;
            }
        }
        __syncthreads();
        #pragma unroll
        for (int s = 0; s < 2; ++s) {
            short8 af[2], bfr[4];
            #pragma unroll
            for (int mt = 0; mt < 2; ++mt)
                af[mt] = as[(wr * 32 + mt * 16 + m) * 8 + ((s * 4 + q) ^ (m & 7))];
            #pragma unroll
            for (int nt = 0; nt < 4; ++nt)
                bfr[nt] = bs[(wc * 64 + nt * 16 + m) * 8 + ((s * 4 + q) ^ (m & 7))];
            #pragma unroll
            for (int mt = 0; mt < 2; ++mt)
                #pragma unroll
                for (int nt = 0; nt < 4; ++nt)
                    acc[mt][nt] = __builtin_amdgcn_mfma_f32_16x16x32_bf16(af[mt], bfr[nt], acc[mt][nt], 0, 0, 0);
        }
        __syncthreads();
    }

    if (mat < 2) {
        // per-head LN: wave's 64-col span == one head; stats via quad shuffles
        const float* g = (mat == 0) ? qg : kg;
        const float* be = (mat == 0) ? qbeta : kbeta;
        unsigned short* Y = (mat == 0) ? Qb : Kb;
        float gv[4], bv[4];
        #pragma unroll
        for (int nt = 0; nt < 4; ++nt) { gv[nt] = g[nt * 16 + m]; bv[nt] = be[nt * 16 + m]; }
        #pragma unroll
        for (int mt = 0; mt < 2; ++mt) {
            #pragma unroll
            for (int r = 0; r < 4; ++r) {
                float s = 0.f, sq = 0.f;
                #pragma unroll
                for (int nt = 0; nt < 4; ++nt) { const float v = acc[mt][nt][r]; s += v; sq += v * v; }
                s  += __shfl_xor(s, 1);  s  += __shfl_xor(s, 2);  s  += __shfl_xor(s, 4);  s  += __shfl_xor(s, 8);
                sq += __shfl_xor(sq, 1); sq += __shfl_xor(sq, 2); sq += __shfl_xor(sq, 4); sq += __shfl_xor(sq, 8);
                const float mean = s * (1.f / HD);
                const float var  = sq * (1.f / HD) - mean * mean;
                const float rr   = rsqrtf(var + EPS);
                const int grow = row0 + wr * 32 + mt * 16 + q * 4 + r;
                #pragma unroll
                for (int nt = 0; nt < 4; ++nt) {
                    float v = (acc[mt][nt][r] - mean) * rr * gv[nt] + bv[nt];
                    if (mat == 0) v *= QSCALE;
                    Y[(size_t)grow * DIM + col0 + wc * 64 + nt * 16 + m] = f2bf(v);
                }
            }
        }
    } else {
        // V: transpose via LDS (row stride 88 shorts), coalesced VT store
        unsigned short* vt = (unsigned short*)smem;
        #pragma unroll
        for (int mt = 0; mt < 2; ++mt)
            #pragma unroll
            for (int nt = 0; nt < 4; ++nt) {
                const int c  = wc * 64 + nt * 16 + m;
                const int rw = wr * 32 + mt * 16 + q * 4;
                *(unsigned int*)(vt + c * 88 + rw)     = pk2(acc[mt][nt][0], acc[mt][nt][1]);
                *(unsigned int*)(vt + c * 88 + rw + 2) = pk2(acc[mt][nt][2], acc[mt][nt][3]);
            }
        __syncthreads();
        #pragma unroll
        for (int p = 0; p < 4; ++p) {
            const int idx = tid + p * 256;      // 1024 items = 128 cols x 8
            const int c = idx >> 3, sg = idx & 7;
            *(short8*)(VTb + (size_t)(col0 + c) * NBANK + row0 + sg * 8) =
                *(const short8*)(vt + c * 88 + sg * 8);
        }
    }
}

// ---------------------------------------------------------------------------
// attn_kernel: MFMA-bf16 flash attention, no-max softmax, SPLIT-4 over bank.
// grid (512, 4): x -> (head, 64-row group), y -> bank quarter (1024 rows).
// Writes unnormalized bf16 O-partials + per-(row,head) partial sums.
// ---------------------------------------------------------------------------
__global__ __launch_bounds__(256) void attn_kernel(
    const unsigned short* __restrict__ Qb, const unsigned short* __restrict__ Kb,
    const unsigned short* __restrict__ VTb, unsigned short* __restrict__ AOp,
    float* __restrict__ sums)
{
    __shared__ short8 ks [512];   // 8 KB  K chunk  [n][hd]  swizzled
    __shared__ short8 vts[512];   // 8 KB  V^T chunk [hd][n] swizzled
    __shared__ short8 ps [512];   // 8 KB  P, per-wave [16][64] swizzled
    const int tid  = threadIdx.x;
    const int w    = tid >> 6;
    const int lane = tid & 63;
    const int m    = lane & 15;
    const int q    = lane >> 4;
    const int h    = blockIdx.x & 7;
    const int row0 = (blockIdx.x >> 3) * 64;
    const int part = blockIdx.y;
    const int base0 = part * 1024;

    short8 qf[2];
    #pragma unroll
    for (int s = 0; s < 2; ++s)
        qf[s] = *(const short8*)(Qb + (size_t)(row0 + w * 16 + m) * DIM + h * HD + s * 32 + q * 8);

    floatx4 of[4];
    float sump[4];
    #pragma unroll
    for (int t = 0; t < 4; ++t) of[t] = (floatx4){0.f, 0.f, 0.f, 0.f};
    #pragma unroll
    for (int r = 0; r < 4; ++r) sump[r] = 0.f;

    unsigned short* psu = (unsigned short*)ps;

    for (int base = base0; base < base0 + 1024; base += 64) {
        __syncthreads();
        #pragma unroll
        for (int it = 0; it < 2; ++it) {
            const int idx = tid + it * 256;
            const int n = idx >> 3, seg = idx & 7, sw = seg ^ (n & 7);
            ks [n * 8 + sw] = *(const short8*)(Kb  + (size_t)(base + n) * DIM  + h * HD + seg * 8);
            vts[n * 8 + sw] = *(const short8*)(VTb + (size_t)(h * HD + n) * NBANK + base + seg * 8);
        }
        __syncthreads();

        floatx4 sc[4];
        #pragma unroll
        for (int t = 0; t < 4; ++t) sc[t] = (floatx4){0.f, 0.f, 0.f, 0.f};
        #pragma unroll
        for (int s = 0; s < 2; ++s) {
            #pragma unroll
            for (int t = 0; t < 4; ++t) {
                const short8 kf = ks[(t * 16 + m) * 8 + ((s * 4 + q) ^ (m & 7))];
                sc[t] = __builtin_amdgcn_mfma_f32_16x16x32_bf16(qf[s], kf, sc[t], 0, 0, 0);
            }
        }

        #pragma unroll
        for (int t = 0; t < 4; ++t) {
            #pragma unroll
            for (int r = 0; r < 4; ++r) {
                const float p = __expf(sc[t][r]);
                sump[r] += p;
                const int row  = q * 4 + r;
                const int colb = t * 2 + (m >> 3);
                psu[(w * 16 + row) * 64 + ((colb ^ (row & 7)) * 8) + (m & 7)] = f2bf(p);
            }
        }

        short8 pf[2];
        #pragma unroll
        for (int s = 0; s < 2; ++s)
            pf[s] = ps[(w * 16 + m) * 8 + ((s * 4 + q) ^ (m & 7))];
        #pragma unroll
        for (int s = 0; s < 2; ++s) {
            #pragma unroll
            for (int t = 0; t < 4; ++t) {
                const short8 vf = vts[(t * 16 + m) * 8 + ((s * 4 + q) ^ (m & 7))];
                of[t] = __builtin_amdgcn_mfma_f32_16x16x32_bf16(pf[s], vf, of[t], 0, 0, 0);
            }
        }
    }

    // epilogue: reduce partial sums across the 16 cols held per lane-group,
    // store raw sums (m==0 lanes) + unnormalized bf16 O-partials.
    #pragma unroll
    for (int r = 0; r < 4; ++r) {
        float s = sump[r];
        s += __shfl_xor(s, 1); s += __shfl_xor(s, 2);
        s += __shfl_xor(s, 4); s += __shfl_xor(s, 8);
        sump[r] = s;
    }
    if (m == 0) {
        #pragma unroll
        for (int r = 0; r < 4; ++r)
            sums[((size_t)part * NQROWS + row0 + w * 16 + q * 4 + r) * NHEAD + h] = sump[r];
    }
    #pragma unroll
    for (int t = 0; t < 4; ++t) {
        #pragma unroll
        for (int r = 0; r < 4; ++r) {
            AOp[(size_t)part * PART_ELEMS +
                (size_t)(row0 + w * 16 + q * 4 + r) * DIM + h * HD + t * 16 + m] = f2bf(of[t][r]);
        }
    }
}

// ---------------------------------------------------------------------------
// combine_kernel: AO = (sum_p O_p) / (sum_p s_p), bf16 out; fused final-LN
// row stats (mean, rstd).  Block = 2 rows x 128 threads.
// ---------------------------------------------------------------------------
__global__ __launch_bounds__(256) void combine_kernel(
    const unsigned short* __restrict__ AOp, const float* __restrict__ sums,
    unsigned short* __restrict__ AO, float* __restrict__ meanv, float* __restrict__ rstdv)
{
    __shared__ float rs[256], rq[256];
    const int tid = threadIdx.x;
    const int row = blockIdx.x * 2 + (tid >> 7);
    const int t   = tid & 127;                 // 4 cols per thread
    const int h   = t >> 4;

    float stot = 0.f;
    #pragma unroll
    for (int p = 0; p < 4; ++p)
        stot += sums[((size_t)p * NQROWS + row) * NHEAD + h];

    float o[4] = {0.f, 0.f, 0.f, 0.f};
    #pragma unroll
    for (int p = 0; p < 4; ++p) {
        const ushort4 u = *(const ushort4*)(AOp + (size_t)p * PART_ELEMS + (size_t)row * DIM + t * 4);
        o[0] += bf2f(u.x); o[1] += bf2f(u.y); o[2] += bf2f(u.z); o[3] += bf2f(u.w);
    }
    const float inv = 1.0f / stot;
    float v0 = o[0] * inv, v1 = o[1] * inv, v2 = o[2] * inv, v3 = o[3] * inv;

    uint2 packed;
    packed.x = pk2(v0, v1); packed.y = pk2(v2, v3);
    *(uint2*)(AO + (size_t)row * DIM + t * 4) = packed;

    rs[tid] = v0 + v1 + v2 + v3;
    rq[tid] = v0 * v0 + v1 * v1 + v2 * v2 + v3 * v3;
    __syncthreads();
    #pragma unroll
    for (int off = 64; off > 0; off >>= 1) {
        if (t < off) { rs[tid] += rs[tid + off]; rq[tid] += rq[tid + off]; }
        __syncthreads();
    }
    if (t == 0) {
        const float mean = rs[tid] * (1.f / DIM);
        const float var  = rq[tid] * (1.f / DIM) - mean * mean;
        meanv[row] = mean;
        rstdv[row] = rsqrtf(var + EPS);
    }
}

// ---------------------------------------------------------------------------
// final_kernel: out = LN_512(AO) @ Wproj^T.  LN uses precomputed stats,
// fused into bf16 A staging.  64x64 tiles, grid (64,8), 4 waves (16 cols each).
// ---------------------------------------------------------------------------
__global__ __launch_bounds__(256) void final_kernel(
    const unsigned short* __restrict__ AO, const float* __restrict__ W,
    const float* __restrict__ meanv, const float* __restrict__ rstdv,
    const float* __restrict__ g, const float* __restrict__ be,
    float* __restrict__ out)
{
    __shared__ short8 fs[1024];            // A [0,512)=64x64, B [512,1024)=64x64
    __shared__ float gls[512], bls[512];
    const int tid  = threadIdx.x;
    const int w    = tid >> 6, lane = tid & 63, m = lane & 15, q = lane >> 4;
    const int row0 = blockIdx.x * 64;
    const int col0 = blockIdx.y * 64;

    #pragma unroll
    for (int i = 0; i < 2; ++i) { gls[tid + i * 256] = g[tid + i * 256]; bls[tid + i * 256] = be[tid + i * 256]; }

    floatx4 acc[4];
    #pragma unroll
    for (int mt = 0; mt < 4; ++mt) acc[mt] = (floatx4){0.f, 0.f, 0.f, 0.f};
    __syncthreads();

    for (int k0 = 0; k0 < DIM; k0 += 64) {
        #pragma unroll
        for (int p = 0; p < 4; ++p) {      // 512 A items + 512 B items
            const int idx = tid + p * 256;
            if (idx < 512) {
                const int row = idx >> 3, seg = idx & 7;
                const short8 a = *(const short8*)(AO + (size_t)(row0 + row) * DIM + k0 + seg * 8);
                const float mm = meanv[row0 + row], rr = rstdv[row0 + row];
                const float* gp = gls + k0 + seg * 8;
                const float* bp = bls + k0 + seg * 8;
                float v[8];
                #pragma unroll
                for (int j = 0; j < 8; ++j)
                    v[j] = (bf2f((unsigned short)a[j]) - mm) * rr * gp[j] + bp[j];
                union { short8 s; unsigned int u[4]; } ta;
                ta.u[0] = pk2(v[0], v[1]); ta.u[1] = pk2(v[2], v[3]);
                ta.u[2] = pk2(v[4], v[5]); ta.u[3] = pk2(v[6], v[7]);
                fs[row * 8 + (seg ^ (row & 7))] = ta.s;
            } else {
                const int j = idx - 512;
                const int row = j >> 3, seg = j & 7;
                const float4* pb = (const float4*)(W + (size_t)(col0 + row) * DIM + k0 + seg * 8);
                const float4 b0 = pb[0], b1 = pb[1];
                union { short8 s; unsigned int u[4]; } tb;
                tb.u[0] = pk2(b0.x, b0.y); tb.u[1] = pk2(b0.z, b0.w);
                tb.u[2] = pk2(b1.x, b1.y); tb.u[3] = pk2(b1.z, b1.w);
                fs[512 + row * 8 + (seg ^ (row & 7))] = tb.s;
            }
        }
        __syncthreads();
        #pragma unroll
        for (int s = 0; s < 2; ++s) {
            short8 af[4];
            #pragma unroll
            for (int mt = 0; mt < 4; ++mt)
                af[mt] = fs[(mt * 16 + m) * 8 + ((s * 4 + q) ^ (m & 7))];
            const short8 bfr = fs[512 + (w * 16 + m) * 8 + ((s * 4 + q) ^ (m & 7))];
            #pragma unroll
            for (int mt = 0; mt < 4; ++mt)
                acc[mt] = __builtin_amdgcn_mfma_f32_16x16x32_bf16(af[mt], bfr, acc[mt], 0, 0, 0);
        }
        __syncthreads();
    }

    #pragma unroll
    for (int mt = 0; mt < 4; ++mt)
        #pragma unroll
        for (int r = 0; r < 4; ++r)
            out[(size_t)(row0 + mt * 16 + q * 4 + r) * DIM + col0 + w * 16 + m] = acc[mt][r];
}

// ---------------------------------------------------------------------------
extern "C" void kernel_launch(void* const* d_in, const int* in_sizes, int n_in,
                              void* d_out, int out_size, void* d_ws, size_t ws_size,
                              hipStream_t stream)
{
    const float* x_q = (const float*)d_in[0];
    const float* x_k = (const float*)d_in[1];
    const float* x_v = (const float*)d_in[2];
    const float* Wq  = (const float*)d_in[3];
    const float* Wk  = (const float*)d_in[4];
    const float* Wv  = (const float*)d_in[5];
    const float* Wp  = (const float*)d_in[6];
    const float* qg  = (const float*)d_in[7];
    const float* qb  = (const float*)d_in[8];
    const float* kg  = (const float*)d_in[9];
    const float* kb  = (const float*)d_in[10];
    const float* ng  = (const float*)d_in[11];
    const float* nb  = (const float*)d_in[12];
    float* out = (float*)d_out;

    // ws: Qb|Kb|VTb (bf16, 4 MB each) | AOp (bf16, 4x4 MB) | sums 512 KB |
    //     stats 32 KB.  AO (bf16) aliases Qb (dead after attn). Total ~28.6 MB.
    unsigned short* Qb   = (unsigned short*)d_ws;
    unsigned short* Kb   = Qb  + (size_t)NQROWS * DIM;
    unsigned short* VTb  = Kb  + (size_t)NBANK * DIM;
    unsigned short* AOp  = VTb + (size_t)NBANK * DIM;
    float*          sums = (float*)(AOp + (size_t)4 * PART_ELEMS);
    float*          meanv = sums + (size_t)4 * NQROWS * NHEAD;
    float*          rstdv = meanv + NQROWS;
    unsigned short* AO   = Qb;   // alias: Qb dead after attn_kernel

    qkv_kernel<<<dim3(64, 12), 256, 0, stream>>>(x_q, x_k, x_v, Wq, Wk, Wv,
                                                 qg, qb, kg, kb, Qb, Kb, VTb);
    attn_kernel<<<dim3(512, 4), 256, 0, stream>>>(Qb, Kb, VTb, AOp, sums);
    combine_kernel<<<NQROWS / 2, 256, 0, stream>>>(AOp, sums, AO, meanv, rstdv);
    final_kernel<<<dim3(64, 8), 256, 0, stream>>>(AO, Wp, meanv, rstdv, ng, nb, out);
}